// Round 1
// baseline (407.403 us; speedup 1.0000x reference)
//
#include <hip/hip_runtime.h>
#include <stdint.h>

typedef int int32x4  __attribute__((ext_vector_type(4)));
typedef int int32x16 __attribute__((ext_vector_type(16)));

#define IN_F   4096
#define OUT_F  4096
#define ROWS   8192   /* 4 * 2048 */

#define BM 256
#define BN 256
#define BK 64
#define NT (IN_F / BK)        /* 64 K-tiles */
#define TILE_LDS 32768        /* A 16KB + B 16KB per tile */
#define LDS_TOTAL (4 * TILE_LDS) /* quad buffer = 128 KB (dynamic) */

// async global->LDS, 16B per lane; LDS dest must be lane-contiguous (m104/m108)
#define GLOAD_LDS16(g, l)                                                      \
  __builtin_amdgcn_global_load_lds(                                            \
      (const __attribute__((address_space(1))) void*)(g),                      \
      (__attribute__((address_space(3))) void*)(l), 16, 0, 0)

// counted vmcnt wait (T4): asm memory clobber is the IR fence that keeps LDS
// reads / DMA issues from crossing iterations; sched_barrier pins the MIR
// scheduler (rule 18).
#define WAITV(n)                                                               \
  do {                                                                         \
    asm volatile("s_waitcnt vmcnt(" #n ")" ::: "memory");                      \
    __builtin_amdgcn_sched_barrier(0);                                         \
  } while (0)

__device__ __forceinline__ int pack4i(int a, int b, int c, int d) {
  return (a & 0xff) | ((b & 0xff) << 8) | ((c & 0xff) << 16) | (d << 24);
}

// ---- fused conversion: x int32->int8 and w fp32->int8, grid-stride (G11) ----
#define CVT_BLOCKS 2048
#define CVT_NX 8388608   /* 8192*4096/4 int4 chunks */
#define CVT_NT 12582912  /* + 4096*4096/4 float4 chunks */
__global__ void __launch_bounds__(256) cvt_kernel(const int4* __restrict__ x,
                                                  const float4* __restrict__ w,
                                                  int* __restrict__ ox,
                                                  int* __restrict__ ow) {
  size_t i = (size_t)blockIdx.x * 256 + threadIdx.x;
  for (; i < CVT_NT; i += (size_t)CVT_BLOCKS * 256) {
    if (i < CVT_NX) {            // wave-uniform: CVT_NX % 256 == 0
      int4 a = x[i];
      ox[i] = pack4i(a.x, a.y, a.z, a.w);
    } else {
      size_t j = i - CVT_NX;
      float4 a = w[j];
      ow[j] = pack4i(__float2int_rn(a.x), __float2int_rn(a.y),
                     __float2int_rn(a.z), __float2int_rn(a.w));
    }
  }
}

// ---- i8 MFMA GEMM: C[m,n] = sum_k A[m,k]*B[n,k] (both row-major [rows][K]) --
// 256x256 tile, BK=64, 8 waves (2x4), per-wave 128x64 via 4x2 tiles of
// mfma_i32_32x32x32_i8 (reads:MFMA = 6:8 per ks, vs 1:1 before).
// Quad-buffered LDS (4 x 32KB, dynamic), prefetch depth 3, ONE raw s_barrier +
// ONE counted s_waitcnt vmcnt(8) per K-tile (T3+T4); never drains in main loop.
// Buffer-rotation safety: issue(t+3) writes buf[(t-1)&3]; its readers (tile
// t-1) completed all lgkm-waited ds_reads before arriving at iteration t's
// barrier; readers of tile t+3 are guarded by vmcnt(8)+barrier at iter t+3.
// LDS swizzle (both-sides, rule 21): chunk (r, c in [0,4)) stored at 16B-unit
// position r*4 + (c ^ ((r>>1)&3)); applied by pre-swizzling the GLOBAL source
// (global_load_lds dest stays lane-linear) and by the swizzled read index.
// Per-16-lane quarter this is 2-way (free, m136); 4-way per 32 is irreducible
// for 32-row x 16B reads on 32 banks.
// A-frag (inherited from the verified kernel): m = lane&31, k-bytes at
// ks*32 + (lane>>5)*16.  C/D: col = lane&31, row = (reg&3)+8*(reg>>2)+4*(lane>>5).
__global__ void __launch_bounds__(512) gemm_i8_kernel(
    const int8_t* __restrict__ A8, const int8_t* __restrict__ B8,
    const float* __restrict__ bias, const float* __restrict__ alpha_p,
    int* __restrict__ out) {
  extern __shared__ int8_t lds[];

  const int t    = threadIdx.x;
  const int wave = t >> 6;
  const int lane = t & 63;
  const int l31  = lane & 31;
  const int hi   = lane >> 5;   // 0..1
  const int wm   = wave >> 2;   // 0..1  (M rows of waves)
  const int wn   = wave & 3;    // 0..3  (N cols of waves)

  // XCD-aware bijective swizzle (T1): 512 blocks, 8 XCDs -> each XCD gets 64
  // consecutive work ids = 4 A-panels x 16 B-panels (L2-resident staging).
  const int flat = blockIdx.y * gridDim.x + blockIdx.x;  // 0..511
  const int wid  = (flat & 7) * 64 + (flat >> 3);
  const int bm   = wid >> 4;    // 0..31
  const int bn   = wid & 15;    // 0..15

  // staging: per tile, A = 2 rounds of 512x16B, B = 2 rounds. Thread t stages
  // LDS chunk p = j*512 + t  ->  logical row r = j*128 + (t>>2),
  // c = (t&3) ^ ((t>>3)&3)  (inverse of the read swizzle; j-independent).
  const int rS = t >> 2;                              // 0..127
  const int cS = ((t & 3) ^ ((t >> 3) & 3)) * 16;
  const int8_t* ga = A8 + (size_t)(bm * BM + rS) * IN_F + cS;
  const int8_t* gb = B8 + (size_t)(bn * BN + rS) * IN_F + cS;
  const int ldst = t * 16;

  const int swz   = (l31 >> 1) & 3;
  const int arow0 = (wm * 128 + l31) * 4;   // 16B-unit index; +mi*128 per mi
  const int brow0 = (wn * 64  + l31) * 4;   // +ni*128 per ni

  int32x16 acc[4][2] = {};

  auto issue = [&](int tile) {
    int8_t* base = lds + (tile & 3) * TILE_LDS;
    const int k0 = tile * BK;
    GLOAD_LDS16(ga + k0,                      base + ldst);
    GLOAD_LDS16(ga + k0 + (size_t)128 * IN_F, base + 8192  + ldst);
    GLOAD_LDS16(gb + k0,                      base + 16384 + ldst);
    GLOAD_LDS16(gb + k0 + (size_t)128 * IN_F, base + 24576 + ldst);
  };

  auto compute = [&](int tile) {
    const int32x4* As4 = (const int32x4*)(lds + (tile & 3) * TILE_LDS);
    const int32x4* Bs4 = (const int32x4*)(lds + (tile & 3) * TILE_LDS + 16384);
#pragma unroll
    for (int ks = 0; ks < 2; ++ks) {
      const int ksw = (ks * 2 + hi) ^ swz;
      int32x4 af[4], bf[2];
#pragma unroll
      for (int i = 0; i < 4; ++i) af[i] = As4[arow0 + i * 128 + ksw];
#pragma unroll
      for (int i = 0; i < 2; ++i) bf[i] = Bs4[brow0 + i * 128 + ksw];
      __builtin_amdgcn_s_setprio(1);   // T5: favor MFMA wave vs staging waves
#pragma unroll
      for (int mi = 0; mi < 4; ++mi)
#pragma unroll
        for (int ni = 0; ni < 2; ++ni)
          acc[mi][ni] = __builtin_amdgcn_mfma_i32_32x32x32_i8(
              af[mi], bf[ni], acc[mi][ni], 0, 0, 0);
      __builtin_amdgcn_s_setprio(0);
    }
  };

  // prologue: tiles 0..2 in flight (12 vmem ops/wave)
  issue(0); issue(1); issue(2);

  // main loop: wait tile t (own share) -> barrier (all waves' shares landed,
  // everyone done reading buf[(t-1)&3]) -> issue t+3 -> compute t.
  for (int tt = 0; tt < NT - 3; ++tt) {
    WAITV(8);
    __builtin_amdgcn_s_barrier();
    __builtin_amdgcn_sched_barrier(0);
    issue(tt + 3);
    compute(tt);
  }
  // epilogue peel: drain 8 -> 4 -> 0 (vmcnt immediates must be literals)
  WAITV(8);
  __builtin_amdgcn_s_barrier();
  __builtin_amdgcn_sched_barrier(0);
  compute(NT - 3);
  WAITV(4);
  __builtin_amdgcn_s_barrier();
  __builtin_amdgcn_sched_barrier(0);
  compute(NT - 2);
  WAITV(0);
  __builtin_amdgcn_s_barrier();
  __builtin_amdgcn_sched_barrier(0);
  compute(NT - 1);

  // epilogue: C/D col = lane&31, row = (reg&3) + 8*(reg>>2) + 4*hi
  const float alpha = *alpha_p;
#pragma unroll
  for (int mi = 0; mi < 4; ++mi) {
    const int rowt = bm * BM + wm * 128 + mi * 32 + hi * 4;
#pragma unroll
    for (int ni = 0; ni < 2; ++ni) {
      const int col = bn * BN + wn * 64 + ni * 32 + l31;
      const float bv = bias[col];
#pragma unroll
      for (int r = 0; r < 16; ++r) {
        const int row = rowt + (r & 3) + 8 * (r >> 2);
        float v = rintf((float)acc[mi][ni][r] * alpha + bv);
        v = fminf(fmaxf(v, -128.f), 127.f);
        out[(size_t)row * OUT_F + col] = (int)v;
      }
    }
  }
}

extern "C" void kernel_launch(void* const* d_in, const int* in_sizes, int n_in,
                              void* d_out, int out_size, void* d_ws, size_t ws_size,
                              hipStream_t stream) {
  const int*   x     = (const int*)d_in[0];    // [8192, 4096] int8-valued
  const float* w     = (const float*)d_in[1];  // [4096, 4096] int8-valued
  const float* bias  = (const float*)d_in[2];  // [4096]
  const float* alpha = (const float*)d_in[3];  // scalar
  int* out = (int*)d_out;                      // [8192, 4096] int32 (int8 values)

  int8_t* x8 = (int8_t*)d_ws;                        // 33,554,432 B
  int8_t* w8 = x8 + (size_t)ROWS * IN_F;             // 16,777,216 B (total 48 MB)

  static bool attr_done = false;
  if (!attr_done) {
    (void)hipFuncSetAttribute(reinterpret_cast<const void*>(gemm_i8_kernel),
                              hipFuncAttributeMaxDynamicSharedMemorySize,
                              LDS_TOTAL);
    attr_done = true;
  }

  cvt_kernel<<<CVT_BLOCKS, 256, 0, stream>>>((const int4*)x, (const float4*)w,
                                             (int*)x8, (int*)w8);

  dim3 grid(OUT_F / BN, ROWS / BM);  // (16, 32) = 512 blocks, 2 clean rounds
  gemm_i8_kernel<<<grid, 512, LDS_TOTAL, stream>>>(x8, w8, bias, alpha, out);
}